// Round 1
// baseline (454.935 us; speedup 1.0000x reference)
//
#include <hip/hip_runtime.h>

// Problem constants (from reference)
#define N0 409600
#define N1 40960
#define N2 4096
#define KF 10          // sampled fanout
#define IN 512
#define HID 128
#define NCLS 64

static __device__ __forceinline__ float4 f4_zero() { return make_float4(0.f, 0.f, 0.f, 0.f); }

// ---------------------------------------------------------------------------
// Kernel 1: fused block 0.
//   agg = mean_k(embed[nbr0] - h0_hist[nbr0]) + agg_h0      [32 nodes/block]
//   h   = agg @ W1 + b1                                     (512 -> 128)
//   h1p = concat(h, relu(h)) - h1_hist                      -> ws [N1, 256]
// 256 threads = 4 waves. Phase 1: each wave aggregates 8 nodes into LDS
// (lane covers 8 contiguous floats via two float4 loads -> coalesced 2KB rows).
// Phase 2: register-tiled f32 GEMV; thread = 4 rows x 4 cols.
// ---------------------------------------------------------------------------
__global__ __launch_bounds__(256) void k_block0(
    const float* __restrict__ embed, const float* __restrict__ h0_hist,
    const float* __restrict__ h1_hist, const float* __restrict__ agg_h0,
    const float* __restrict__ W1, const float* __restrict__ b1,
    const int* __restrict__ nbr0, float* __restrict__ h1p)
{
    __shared__ float A[32][IN];          // 64 KB aggregated-activation tile
    const int t = threadIdx.x;
    const int wave = t >> 6;
    const int lane = t & 63;
    const int base_node = blockIdx.x * 32;

    // ---- phase 1: gather + mean + add agg_h0 ----
    for (int i = 0; i < 8; ++i) {
        const int nl = wave * 8 + i;
        const int node = base_node + nl;
        float4 acc0 = f4_zero(), acc1 = f4_zero();
        const int nb_off = node * KF;
        const int col = lane * 8;
        for (int j = 0; j < KF; ++j) {
            const int idx = nbr0[nb_off + j];
            const float4* e = (const float4*)(embed   + (long long)idx * IN + col);
            const float4* g = (const float4*)(h0_hist + (long long)idx * IN + col);
            const float4 e0 = e[0], e1 = e[1];
            const float4 g0 = g[0], g1 = g[1];
            acc0.x += e0.x - g0.x; acc0.y += e0.y - g0.y;
            acc0.z += e0.z - g0.z; acc0.w += e0.w - g0.w;
            acc1.x += e1.x - g1.x; acc1.y += e1.y - g1.y;
            acc1.z += e1.z - g1.z; acc1.w += e1.w - g1.w;
        }
        const float s = 1.0f / (float)KF;
        const float4* ah = (const float4*)(agg_h0 + (long long)node * IN + col);
        const float4 a0 = ah[0], a1 = ah[1];
        float4 r0, r1;
        r0.x = acc0.x * s + a0.x; r0.y = acc0.y * s + a0.y;
        r0.z = acc0.z * s + a0.z; r0.w = acc0.w * s + a0.w;
        r1.x = acc1.x * s + a1.x; r1.y = acc1.y * s + a1.y;
        r1.z = acc1.z * s + a1.z; r1.w = acc1.w * s + a1.w;
        *(float4*)&A[nl][col]     = r0;
        *(float4*)&A[nl][col + 4] = r1;
    }
    __syncthreads();

    // ---- phase 2: GEMV 512 -> 128 + bias + concat/relu - h1_hist ----
    const int c0 = (t & 31) * 4;   // output col group (covers 128)
    const int rg = t >> 5;         // row group 0..7 (4 rows each -> 32)
    float4 acc[4];
    acc[0] = f4_zero(); acc[1] = f4_zero(); acc[2] = f4_zero(); acc[3] = f4_zero();

    #pragma unroll 4
    for (int k = 0; k < IN; ++k) {
        const float4 w = *(const float4*)&W1[k * HID + c0];
        #pragma unroll
        for (int i = 0; i < 4; ++i) {
            const float a = A[rg * 4 + i][k];
            acc[i].x += a * w.x; acc[i].y += a * w.y;
            acc[i].z += a * w.z; acc[i].w += a * w.w;
        }
    }

    const float4 bb = *(const float4*)&b1[c0];
    #pragma unroll
    for (int i = 0; i < 4; ++i) {
        const int node = base_node + rg * 4 + i;
        float4 h;
        h.x = acc[i].x + bb.x; h.y = acc[i].y + bb.y;
        h.z = acc[i].z + bb.z; h.w = acc[i].w + bb.w;
        const float4 hh0 = *(const float4*)&h1_hist[node * (2 * HID) + c0];
        const float4 hh1 = *(const float4*)&h1_hist[node * (2 * HID) + HID + c0];
        float4 o0, o1;
        o0.x = h.x - hh0.x; o0.y = h.y - hh0.y;
        o0.z = h.z - hh0.z; o0.w = h.w - hh0.w;
        o1.x = fmaxf(h.x, 0.f) - hh1.x; o1.y = fmaxf(h.y, 0.f) - hh1.y;
        o1.z = fmaxf(h.z, 0.f) - hh1.z; o1.w = fmaxf(h.w, 0.f) - hh1.w;
        *(float4*)&h1p[node * (2 * HID) + c0]       = o0;
        *(float4*)&h1p[node * (2 * HID) + HID + c0] = o1;
    }
}

// ---------------------------------------------------------------------------
// Kernel 2: fused block 1.
//   agg = mean_k(h1p[nbr1]) + agg_h1          [16 nodes/block]
//   out = agg @ W2 + b2                        (256 -> 64)
// h1p is 42 MB -> L3-resident, gather is cheap.
// ---------------------------------------------------------------------------
__global__ __launch_bounds__(256) void k_block1(
    const float* __restrict__ h1p, const float* __restrict__ agg_h1,
    const float* __restrict__ W2, const float* __restrict__ b2,
    const int* __restrict__ nbr1, float* __restrict__ out)
{
    __shared__ float B[16][2 * HID + 4];   // pad to 260 floats: kill 4-way bank alias
    const int t = threadIdx.x;
    const int wave = t >> 6;
    const int lane = t & 63;
    const int base_node = blockIdx.x * 16;

    // ---- phase 1: gather + mean + add agg_h1 ----
    for (int i = 0; i < 4; ++i) {
        const int nl = wave * 4 + i;
        const int node = base_node + nl;
        float4 acc = f4_zero();
        const int nb_off = node * KF;
        const int col = lane * 4;  // 64 lanes x 4 floats = 256
        for (int j = 0; j < KF; ++j) {
            const int idx = nbr1[nb_off + j];
            const float4 v = *(const float4*)&h1p[idx * (2 * HID) + col];
            acc.x += v.x; acc.y += v.y; acc.z += v.z; acc.w += v.w;
        }
        const float s = 1.0f / (float)KF;
        const float4 g = *(const float4*)&agg_h1[node * (2 * HID) + col];
        float4 r;
        r.x = acc.x * s + g.x; r.y = acc.y * s + g.y;
        r.z = acc.z * s + g.z; r.w = acc.w * s + g.w;
        *(float4*)&B[nl][col] = r;
    }
    __syncthreads();

    // ---- phase 2: GEMV 256 -> 64 + bias ----
    const int r = t >> 4;          // node row 0..15
    const int c0 = (t & 15) * 4;   // col group covers 64
    float4 acc = f4_zero();
    #pragma unroll 4
    for (int k = 0; k < 2 * HID; ++k) {
        const float a = B[r][k];
        const float4 w = *(const float4*)&W2[k * NCLS + c0];
        acc.x += a * w.x; acc.y += a * w.y;
        acc.z += a * w.z; acc.w += a * w.w;
    }
    const float4 bb = *(const float4*)&b2[c0];
    float4 o;
    o.x = acc.x + bb.x; o.y = acc.y + bb.y;
    o.z = acc.z + bb.z; o.w = acc.w + bb.w;
    const int node = base_node + r;
    *(float4*)&out[node * NCLS + c0] = o;
}

extern "C" void kernel_launch(void* const* d_in, const int* in_sizes, int n_in,
                              void* d_out, int out_size, void* d_ws, size_t ws_size,
                              hipStream_t stream) {
    const float* embed   = (const float*)d_in[0];
    const float* h0_hist = (const float*)d_in[1];
    const float* h1_hist = (const float*)d_in[2];
    const float* agg_h0  = (const float*)d_in[3];
    const float* agg_h1  = (const float*)d_in[4];
    const float* W1      = (const float*)d_in[5];
    const float* b1      = (const float*)d_in[6];
    const float* W2      = (const float*)d_in[7];
    const float* b2      = (const float*)d_in[8];
    const int*   nbr0    = (const int*)d_in[9];
    const int*   nbr1    = (const int*)d_in[10];
    float* out = (float*)d_out;

    // ws: h1p [N1, 256] f32 = 41.9 MB
    float* h1p = (float*)d_ws;

    k_block0<<<N1 / 32, 256, 0, stream>>>(embed, h0_hist, h1_hist, agg_h0,
                                          W1, b1, nbr0, h1p);
    k_block1<<<N2 / 16, 256, 0, stream>>>(h1p, agg_h1, W2, b2, nbr1, out);
}